// Round 1
// baseline (3894.802 us; speedup 1.0000x reference)
//
#include <hip/hip_runtime.h>
#include <cstdint>
#include <cstddef>

#define DD    1024
#define HDIM  64
#define NHEAD 16
#define LTXT  512
#define LIMG  2048
#define LTOT  2560
#define DMLP  4096

__device__ __forceinline__ float geluf(float x) {
  float x3 = x * x * x;
  return 0.5f * x * (1.f + tanhf(0.7978845608028654f * (x + 0.044715f * x3)));
}

// ---------------- mod GEMV: m = silu(vec) @ W + b, per stream ----------------
// grid (24, 2): x = 256-col tile, y = stream (0=img, 1=txt)
__global__ __launch_bounds__(256) void mod_gemv(
    const float* __restrict__ vec,
    const float* __restrict__ wi, const float* __restrict__ bi,
    const float* __restrict__ wt, const float* __restrict__ bt,
    float* __restrict__ modout) {
  __shared__ float sv[DD];
  const int s = blockIdx.y;
  const float* W = s ? wt : wi;
  const float* B = s ? bt : bi;
  for (int i = threadIdx.x; i < DD; i += 256) {
    float x = vec[i];
    sv[i] = x / (1.f + __expf(-x));
  }
  __syncthreads();
  const int j = blockIdx.x * 256 + threadIdx.x;
  float acc = B[j];
  for (int i = 0; i < DD; ++i) acc += sv[i] * W[(size_t)i * (6 * DD) + j];
  modout[(size_t)s * (6 * DD) + j] = acc;
}

// ---------------- LN + modulate: out = (1+mod[sc])*(LN(x)*ns+nb) + mod[sh] ----
// one block per row
__global__ __launch_bounds__(256) void ln_mod_kernel(
    const float* __restrict__ X, float* __restrict__ out,
    const float* __restrict__ ns, const float* __restrict__ nb,
    const float* __restrict__ modv, int sh_off, int sc_off) {
  __shared__ float red[8];
  const int r = blockIdx.x, tid = threadIdx.x;
  const float* x = X + (size_t)r * DD;
  float v[4];
  float s = 0.f, sq = 0.f;
#pragma unroll
  for (int i = 0; i < 4; ++i) {
    v[i] = x[tid + i * 256];
    s += v[i];
    sq += v[i] * v[i];
  }
#pragma unroll
  for (int o = 32; o; o >>= 1) {
    s += __shfl_xor(s, o);
    sq += __shfl_xor(sq, o);
  }
  if ((tid & 63) == 0) {
    red[tid >> 6] = s;
    red[4 + (tid >> 6)] = sq;
  }
  __syncthreads();
  s = red[0] + red[1] + red[2] + red[3];
  sq = red[4] + red[5] + red[6] + red[7];
  const float mu = s * (1.f / DD);
  const float var = sq * (1.f / DD) - mu * mu;
  const float rstd = rsqrtf(var + 1e-6f);
  float* o = out + (size_t)r * DD;
#pragma unroll
  for (int i = 0; i < 4; ++i) {
    const int c = tid + i * 256;
    const float ln = (v[i] - mu) * rstd * ns[c] + nb[c];
    o[c] = (1.f + modv[sc_off + c]) * ln + modv[sh_off + c];
  }
}

// ---------------- 128x128x8 fp32 tiled GEMM: C = A@W + bias [, gelu] --------
// grid (N/128, M/128), 256 threads, 8x8 microtile
__global__ __launch_bounds__(256) void gemm128(
    const float* __restrict__ A, int lda,
    const float* __restrict__ W, int ldw,
    const float* __restrict__ bias,
    float* __restrict__ C, int ldc, int K, int mode) {
  __shared__ float As[8][132];
  __shared__ float Bs[8][132];
  const int tid = threadIdx.x;
  const int bn = blockIdx.x, bm = blockIdx.y;
  const float* Ab = A + (size_t)bm * 128 * lda;
  const float* Wb = W + (size_t)bn * 128;
  const int tx = tid & 15, ty = tid >> 4;
  float acc[8][8];
#pragma unroll
  for (int i = 0; i < 8; ++i)
#pragma unroll
    for (int j = 0; j < 8; ++j) acc[i][j] = 0.f;

  for (int k0 = 0; k0 < K; k0 += 8) {
#pragma unroll
    for (int i = 0; i < 4; ++i) {
      int e = tid + i * 256;  // 0..1023
      int m = e >> 3, kk = e & 7;
      As[kk][m] = Ab[(size_t)m * lda + k0 + kk];
    }
#pragma unroll
    for (int i = 0; i < 4; ++i) {
      int e = tid + i * 256;
      int kk = e >> 7, n = e & 127;
      Bs[kk][n] = Wb[(size_t)(k0 + kk) * ldw + n];
    }
    __syncthreads();
#pragma unroll
    for (int kk = 0; kk < 8; ++kk) {
      float a[8], b[8];
#pragma unroll
      for (int i = 0; i < 8; ++i) a[i] = As[kk][ty * 8 + i];
#pragma unroll
      for (int j = 0; j < 8; ++j) b[j] = Bs[kk][tx * 8 + j];
#pragma unroll
      for (int i = 0; i < 8; ++i)
#pragma unroll
        for (int j = 0; j < 8; ++j) acc[i][j] += a[i] * b[j];
    }
    __syncthreads();
  }
#pragma unroll
  for (int i = 0; i < 8; ++i) {
    const size_t row = (size_t)bm * 128 + ty * 8 + i;
#pragma unroll
    for (int j = 0; j < 8; ++j) {
      const int col = bn * 128 + tx * 8 + j;
      float val = acc[i][j] + bias[col];
      if (mode == 1) val = geluf(val);
      C[row * ldc + col] = val;
    }
  }
}

// ---------------- scatter qkv (L,3072) -> q/k/v (H, L, 64) ------------------
__global__ __launch_bounds__(256) void qkv_scatter(
    const float* __restrict__ t, float* __restrict__ q, float* __restrict__ k,
    float* __restrict__ v) {
  const int idx = blockIdx.x * 256 + threadIdx.x;  // float4 index
  const int l = idx / 768, c4 = idx % 768;
  const int c = c4 * 4;
  const int which = c >> 10;
  const int rem = c & 1023;
  const int h = rem >> 6, d = rem & 63;
  const float4 val = ((const float4*)t)[idx];
  float* dst = which == 0 ? q : (which == 1 ? k : v);
  *(float4*)&dst[((size_t)h * LTOT + l) * HDIM + d] = val;
}

// ---------------- RMS norm + RoPE on q and k, per (h, l) wave ---------------
__global__ __launch_bounds__(256) void rmsrope(
    float* __restrict__ q, float* __restrict__ k, const float* __restrict__ pe,
    const float* __restrict__ iqs, const float* __restrict__ iks,
    const float* __restrict__ tqs, const float* __restrict__ tks) {
  const int gw = (blockIdx.x * 256 + threadIdx.x) >> 6;
  const int lane = threadIdx.x & 63;
  const int l = gw % LTOT, h = gw / LTOT;
  const float* qs = (l < LTXT) ? tqs : iqs;
  const float* ks = (l < LTXT) ? tks : iks;
  const size_t base = ((size_t)h * LTOT + l) * HDIM + lane;
  const float* peb = pe + (size_t)l * 128 + (lane >> 1) * 4 + (lane & 1) * 2;

  {
    float x = q[base];
    float ss = x * x;
#pragma unroll
    for (int o = 32; o; o >>= 1) ss += __shfl_xor(ss, o);
    float xn = x * rsqrtf(ss * (1.f / HDIM) + 1e-6f) * qs[lane];
    float part = __shfl_xor(xn, 1);
    float x0 = (lane & 1) ? part : xn;
    float x1 = (lane & 1) ? xn : part;
    q[base] = peb[0] * x0 + peb[1] * x1;
  }
  {
    float x = k[base];
    float ss = x * x;
#pragma unroll
    for (int o = 32; o; o >>= 1) ss += __shfl_xor(ss, o);
    float xn = x * rsqrtf(ss * (1.f / HDIM) + 1e-6f) * ks[lane];
    float part = __shfl_xor(xn, 1);
    float x0 = (lane & 1) ? part : xn;
    float x1 = (lane & 1) ? xn : part;
    k[base] = peb[0] * x0 + peb[1] * x1;
  }
}

// ---------------- flash attention fp32: BQ=64, BK=32 ------------------------
// grid (40, 16): x = q tile, y = head. out is (L, D) row-major, col = h*64+d
__global__ __launch_bounds__(256) void attn_kernel(
    const float* __restrict__ q, const float* __restrict__ k,
    const float* __restrict__ v, float* __restrict__ out) {
  __shared__ float Ks[32][68];
  __shared__ float Vs[32][68];
  __shared__ float Ps[64][33];
  const int h = blockIdx.y;
  const int q0 = blockIdx.x * 64;
  const int tid = threadIdx.x;
  const int qr = tid >> 2, quad = tid & 3;
  const size_t hbase = (size_t)h * LTOT;

  float4 qreg[16];
  {
    const float4* qrow = (const float4*)(q + (hbase + q0 + qr) * HDIM);
#pragma unroll
    for (int i = 0; i < 16; ++i) qreg[i] = qrow[i];
  }
  float m_run = -1e30f, l_run = 0.f;
  float acc[16];
#pragma unroll
  for (int i = 0; i < 16; ++i) acc[i] = 0.f;

  for (int kt = 0; kt < LTOT / 32; ++kt) {
    const int k0 = kt * 32;
#pragma unroll
    for (int i = 0; i < 8; ++i) {
      int e = tid + i * 256;
      int r = e >> 6, d = e & 63;
      Ks[r][d] = k[(hbase + k0 + r) * HDIM + d];
      Vs[r][d] = v[(hbase + k0 + r) * HDIM + d];
    }
    __syncthreads();

    float s[8];
#pragma unroll
    for (int jj = 0; jj < 8; ++jj) {
      const int key = quad * 8 + jj;
      float dot = 0.f;
#pragma unroll
      for (int d4 = 0; d4 < 16; ++d4) {
        float4 kv = *(const float4*)&Ks[key][d4 * 4];
        dot += qreg[d4].x * kv.x + qreg[d4].y * kv.y + qreg[d4].z * kv.z +
               qreg[d4].w * kv.w;
      }
      s[jj] = dot * 0.125f;
    }
    float mx = s[0];
#pragma unroll
    for (int jj = 1; jj < 8; ++jj) mx = fmaxf(mx, s[jj]);
    mx = fmaxf(mx, __shfl_xor(mx, 1));
    mx = fmaxf(mx, __shfl_xor(mx, 2));
    const float m_new = fmaxf(m_run, mx);
    const float alpha = __expf(m_run - m_new);
    float psum = 0.f;
#pragma unroll
    for (int jj = 0; jj < 8; ++jj) {
      s[jj] = __expf(s[jj] - m_new);
      psum += s[jj];
    }
    psum += __shfl_xor(psum, 1);
    psum += __shfl_xor(psum, 2);
    l_run = l_run * alpha + psum;
    m_run = m_new;
#pragma unroll
    for (int i = 0; i < 16; ++i) acc[i] *= alpha;
#pragma unroll
    for (int jj = 0; jj < 8; ++jj) Ps[qr][quad * 8 + jj] = s[jj];
    __syncthreads();

#pragma unroll
    for (int j = 0; j < 32; ++j) {
      const float pv = Ps[qr][j];
#pragma unroll
      for (int i4 = 0; i4 < 4; ++i4) {
        float4 vv = *(const float4*)&Vs[j][quad * 16 + i4 * 4];
        acc[i4 * 4 + 0] += pv * vv.x;
        acc[i4 * 4 + 1] += pv * vv.y;
        acc[i4 * 4 + 2] += pv * vv.z;
        acc[i4 * 4 + 3] += pv * vv.w;
      }
    }
    __syncthreads();
  }
  const float inv = 1.f / l_run;
#pragma unroll
  for (int i = 0; i < 16; ++i)
    out[(size_t)(q0 + qr) * DD + h * HDIM + quad * 16 + i] = acc[i] * inv;
}

// ---------------- gated residual: out = xin + g[col] * t --------------------
__global__ __launch_bounds__(256) void resid_gate(
    const float* __restrict__ xin, const float* __restrict__ t,
    const float* __restrict__ g, float* __restrict__ out, int n4) {
  const int idx = blockIdx.x * 256 + threadIdx.x;
  if (idx >= n4) return;
  const int col = (idx * 4) & (DD - 1);
  const float4 a = ((const float4*)xin)[idx];
  const float4 b = ((const float4*)t)[idx];
  const float4 gg = *(const float4*)&g[col];
  float4 r;
  r.x = a.x + gg.x * b.x;
  r.y = a.y + gg.y * b.y;
  r.z = a.z + gg.z * b.z;
  r.w = a.w + gg.w * b.w;
  ((float4*)out)[idx] = r;
}

extern "C" void kernel_launch(void* const* d_in, const int* in_sizes, int n_in,
                              void* d_out, int out_size, void* d_ws,
                              size_t ws_size, hipStream_t stream) {
  const float* img = (const float*)d_in[0];
  const float* txt = (const float*)d_in[1];
  const float* vec = (const float*)d_in[2];
  const float* pe = (const float*)d_in[3];
  const float* i_mod_w = (const float*)d_in[4];
  const float* i_mod_b = (const float*)d_in[5];
  const float* i_n1s = (const float*)d_in[6];
  const float* i_n1b = (const float*)d_in[7];
  const float* i_qkv_w = (const float*)d_in[8];
  const float* i_qkv_b = (const float*)d_in[9];
  const float* i_qs = (const float*)d_in[10];
  const float* i_ks = (const float*)d_in[11];
  const float* i_proj_w = (const float*)d_in[12];
  const float* i_proj_b = (const float*)d_in[13];
  const float* i_n2s = (const float*)d_in[14];
  const float* i_n2b = (const float*)d_in[15];
  const float* i_w1 = (const float*)d_in[16];
  const float* i_b1 = (const float*)d_in[17];
  const float* i_w2 = (const float*)d_in[18];
  const float* i_b2 = (const float*)d_in[19];
  const float* t_mod_w = (const float*)d_in[20];
  const float* t_mod_b = (const float*)d_in[21];
  const float* t_n1s = (const float*)d_in[22];
  const float* t_n1b = (const float*)d_in[23];
  const float* t_qkv_w = (const float*)d_in[24];
  const float* t_qkv_b = (const float*)d_in[25];
  const float* t_qs = (const float*)d_in[26];
  const float* t_ks = (const float*)d_in[27];
  const float* t_proj_w = (const float*)d_in[28];
  const float* t_proj_b = (const float*)d_in[29];
  const float* t_n2s = (const float*)d_in[30];
  const float* t_n2b = (const float*)d_in[31];
  const float* t_w1 = (const float*)d_in[32];
  const float* t_b1 = (const float*)d_in[33];
  const float* t_w2 = (const float*)d_in[34];
  const float* t_b2 = (const float*)d_in[35];

  float* ws = (float*)d_ws;
  const size_t LD = (size_t)LTOT * DD;  // 2,621,440
  float* modb = ws;                     // 2*6144 (+pad)
  float* xm = ws + 16384;               // (L, D): xm, then attn out
  float* qb = xm + LD;                  // q, then h (ln2 out)
  float* kb = qb + LD;                  // k, then mlp2 out
  float* vb = kb + LD;                  // v
  float* mid = vb + LD;                 // (L, 3072) qkv tmp / (L,D) proj tmp / (L, 4096) mlp mid
  float* out_img = (float*)d_out;
  float* out_txt = out_img + (size_t)LIMG * DD;

  // 1. modulation vectors
  mod_gemv<<<dim3(24, 2), 256, 0, stream>>>(vec, i_mod_w, i_mod_b, t_mod_w,
                                            t_mod_b, modb);
  // 2. LN1 + modulate -> xm (txt rows 0..511, img rows 512..2559)
  ln_mod_kernel<<<LTXT, 256, 0, stream>>>(txt, xm, t_n1s, t_n1b, modb + 6144, 0,
                                          1024);
  ln_mod_kernel<<<LIMG, 256, 0, stream>>>(img, xm + (size_t)LTXT * DD, i_n1s,
                                          i_n1b, modb, 0, 1024);
  // 3. QKV GEMMs -> mid (L, 3072)
  gemm128<<<dim3(24, 4), 256, 0, stream>>>(xm, DD, t_qkv_w, 3 * DD, t_qkv_b,
                                           mid, 3 * DD, DD, 0);
  gemm128<<<dim3(24, 16), 256, 0, stream>>>(xm + (size_t)LTXT * DD, DD, i_qkv_w,
                                            3 * DD, i_qkv_b,
                                            mid + (size_t)LTXT * 3 * DD, 3 * DD,
                                            DD, 0);
  // 4. scatter to q/k/v (H, L, 64)
  qkv_scatter<<<7680, 256, 0, stream>>>(mid, qb, kb, vb);
  // 5. RMS norm + RoPE on q, k
  rmsrope<<<10240, 256, 0, stream>>>(qb, kb, pe, i_qs, i_ks, t_qs, t_ks);
  // 6. attention -> xm (L, D)
  attn_kernel<<<dim3(40, 16), 256, 0, stream>>>(qb, kb, vb, xm);
  // 7. proj GEMMs -> mid (L, D)
  gemm128<<<dim3(8, 4), 256, 0, stream>>>(xm, DD, t_proj_w, DD, t_proj_b, mid,
                                          DD, DD, 0);
  gemm128<<<dim3(8, 16), 256, 0, stream>>>(xm + (size_t)LTXT * DD, DD, i_proj_w,
                                           DD, i_proj_b, mid + (size_t)LTXT * DD,
                                           DD, DD, 0);
  // 8. residual 1 -> d_out
  resid_gate<<<2048, 256, 0, stream>>>(img, mid + (size_t)LTXT * DD,
                                       modb + 2048, out_img, LIMG * DD / 4);
  resid_gate<<<512, 256, 0, stream>>>(txt, mid, modb + 6144 + 2048, out_txt,
                                      LTXT * DD / 4);
  // 9. LN2 + modulate -> qb (h buffer)
  ln_mod_kernel<<<LTXT, 256, 0, stream>>>(out_txt, qb, t_n2s, t_n2b,
                                          modb + 6144, 3072, 4096);
  ln_mod_kernel<<<LIMG, 256, 0, stream>>>(out_img, qb + (size_t)LTXT * DD,
                                          i_n2s, i_n2b, modb, 3072, 4096);
  // 10. MLP1 + GELU -> mid (L, 4096)
  gemm128<<<dim3(32, 4), 256, 0, stream>>>(qb, DD, t_w1, DMLP, t_b1, mid, DMLP,
                                           DD, 1);
  gemm128<<<dim3(32, 16), 256, 0, stream>>>(qb + (size_t)LTXT * DD, DD, i_w1,
                                            DMLP, i_b1,
                                            mid + (size_t)LTXT * DMLP, DMLP, DD,
                                            1);
  // 11. MLP2 -> kb (L, D)
  gemm128<<<dim3(8, 4), 256, 0, stream>>>(mid, DMLP, t_w2, DD, t_b2, kb, DD,
                                          DMLP, 0);
  gemm128<<<dim3(8, 16), 256, 0, stream>>>(mid + (size_t)LTXT * DMLP, DMLP,
                                           i_w2, DD, i_b2,
                                           kb + (size_t)LTXT * DD, DD, DMLP, 0);
  // 12. residual 2 (in place on d_out)
  resid_gate<<<2048, 256, 0, stream>>>(out_img, kb + (size_t)LTXT * DD,
                                       modb + 5120, out_img, LIMG * DD / 4);
  resid_gate<<<512, 256, 0, stream>>>(out_txt, kb, modb + 6144 + 5120, out_txt,
                                      LTXT * DD / 4);
}

// Round 2
// 442.147 us; speedup vs baseline: 8.8088x; 8.8088x over previous
//
#include <hip/hip_runtime.h>
#include <cstdint>
#include <cstddef>

#define DD 1024
#define HD 64
#define NH 16
#define LTXT 512
#define LIMG 2048
#define LTOT 2560
#define DMLP 4096

typedef unsigned short u16;
typedef __attribute__((ext_vector_type(8))) __bf16 bf16x8;
typedef __attribute__((ext_vector_type(4))) float f32x4;

__device__ __forceinline__ u16 f2bf(float f) {
  union { float f; uint32_t u; } v; v.f = f;
  uint32_t r = v.u + 0x7FFFu + ((v.u >> 16) & 1u);
  return (u16)(r >> 16);
}
__device__ __forceinline__ float bf2f(u16 u) {
  union { uint32_t u; float f; } v; v.u = ((uint32_t)u) << 16;
  return v.f;
}
__device__ __forceinline__ float geluf(float x) {
  float x3 = x * x * x;
  return 0.5f * x * (1.f + tanhf(0.7978845608028654f * (x + 0.044715f * x3)));
}
__device__ __forceinline__ void gload16(const void* g, void* l) {
  __builtin_amdgcn_global_load_lds(
      (const __attribute__((address_space(1))) void*)g,
      (__attribute__((address_space(3))) void*)l, 16, 0, 0);
}

// ---------------- weight transpose+cast: W (K,N) f32 -> Wt (N,K) bf16 -------
__global__ __launch_bounds__(256) void wcast_t(const float* __restrict__ W,
                                               u16* __restrict__ Wt, int K,
                                               int N) {
  __shared__ float T[32][33];
  const int n0 = blockIdx.x * 32, k0 = blockIdx.y * 32;
  const int tx = threadIdx.x & 31, ty = threadIdx.x >> 5;
#pragma unroll
  for (int i = 0; i < 4; ++i) {
    int r = ty + i * 8;
    T[r][tx] = W[(size_t)(k0 + r) * N + n0 + tx];
  }
  __syncthreads();
#pragma unroll
  for (int i = 0; i < 4; ++i) {
    int r = ty + i * 8;
    Wt[(size_t)(n0 + r) * K + k0 + tx] = f2bf(T[tx][r]);
  }
}

// ---------------- mod GEMV (fp32): m = silu(vec) @ W + b --------------------
__global__ __launch_bounds__(256) void mod_gemv(
    const float* __restrict__ vec, const float* __restrict__ wi,
    const float* __restrict__ bi, const float* __restrict__ wt,
    const float* __restrict__ bt, float* __restrict__ modout) {
  __shared__ float sv[DD];
  const int s = blockIdx.y;
  const float* W = s ? wt : wi;
  const float* B = s ? bt : bi;
  for (int i = threadIdx.x; i < DD; i += 256) {
    float x = vec[i];
    sv[i] = x / (1.f + __expf(-x));
  }
  __syncthreads();
  const int j = blockIdx.x * 256 + threadIdx.x;
  float acc = B[j];
  for (int i = 0; i < DD; ++i) acc += sv[i] * W[(size_t)i * (6 * DD) + j];
  modout[(size_t)s * (6 * DD) + j] = acc;
}

// ---------------- LN + modulate, bf16 out -----------------------------------
__global__ __launch_bounds__(256) void ln_mod_kernel(
    const float* __restrict__ X, u16* __restrict__ out,
    const float* __restrict__ ns, const float* __restrict__ nb,
    const float* __restrict__ modv, int sh_off, int sc_off) {
  __shared__ float red[8];
  const int r = blockIdx.x, tid = threadIdx.x;
  const float* x = X + (size_t)r * DD;
  float v[4];
  float s = 0.f, sq = 0.f;
#pragma unroll
  for (int i = 0; i < 4; ++i) {
    v[i] = x[tid + i * 256];
    s += v[i];
    sq += v[i] * v[i];
  }
#pragma unroll
  for (int o = 32; o; o >>= 1) {
    s += __shfl_xor(s, o);
    sq += __shfl_xor(sq, o);
  }
  if ((tid & 63) == 0) {
    red[tid >> 6] = s;
    red[4 + (tid >> 6)] = sq;
  }
  __syncthreads();
  s = red[0] + red[1] + red[2] + red[3];
  sq = red[4] + red[5] + red[6] + red[7];
  const float mu = s * (1.f / DD);
  const float var = sq * (1.f / DD) - mu * mu;
  const float rstd = rsqrtf(var + 1e-6f);
  u16* o = out + (size_t)r * DD;
#pragma unroll
  for (int i = 0; i < 4; ++i) {
    const int c = tid + i * 256;
    const float ln = (v[i] - mu) * rstd * ns[c] + nb[c];
    o[c] = f2bf((1.f + modv[sc_off + c]) * ln + modv[sh_off + c]);
  }
}

// ---------------- bf16 MFMA GEMM, 128x128 tile, BK=32, dual-stream ----------
// A (Mtot,K) bf16 (txt rows first), Bt* (N,K) bf16, C (Mtot,N) bf16
__global__ __launch_bounds__(256) void gemm_mfma(
    const u16* __restrict__ A, const u16* __restrict__ BtT,
    const u16* __restrict__ BtI, const float* __restrict__ biasT,
    const float* __restrict__ biasI, u16* __restrict__ C, int K, int N,
    int gelu) {
  __shared__ __align__(16) u16 As[128 * 32];
  __shared__ __align__(16) u16 Bs[128 * 32];
  const int tid = threadIdx.x, lane = tid & 63, wave = tid >> 6;
  const int bn = blockIdx.x, bm = blockIdx.y;
  const u16* Bt = (bm < (LTXT / 128)) ? BtT : BtI;
  const float* bias = (bm < (LTXT / 128)) ? biasT : biasI;
  const int wm = wave >> 1, wn = wave & 1;
  const int lr = lane & 15, lk = lane >> 4;
  f32x4 acc[4][4] = {};
  const size_t a0 = (size_t)bm * 128;
  const size_t b0 = (size_t)bn * 128;
  const int srow = lane >> 2, soff = (lane & 3) * 8;
  for (int k0 = 0; k0 < K; k0 += 32) {
#pragma unroll
    for (int j = 0; j < 2; ++j) {
      const int chunk = wave * 2 + j;
      gload16(&A[(a0 + chunk * 16 + srow) * K + k0 + soff], &As[chunk * 512]);
      gload16(&Bt[(b0 + chunk * 16 + srow) * K + k0 + soff], &Bs[chunk * 512]);
    }
    __syncthreads();
    bf16x8 af[4], bfv[4];
#pragma unroll
    for (int m = 0; m < 4; ++m)
      af[m] = *(const bf16x8*)&As[(wm * 64 + m * 16 + lr) * 32 + lk * 8];
#pragma unroll
    for (int n = 0; n < 4; ++n)
      bfv[n] = *(const bf16x8*)&Bs[(wn * 64 + n * 16 + lr) * 32 + lk * 8];
#pragma unroll
    for (int m = 0; m < 4; ++m)
#pragma unroll
      for (int n = 0; n < 4; ++n)
        acc[m][n] = __builtin_amdgcn_mfma_f32_16x16x32_bf16(af[m], bfv[n],
                                                            acc[m][n], 0, 0, 0);
    __syncthreads();
  }
#pragma unroll
  for (int n = 0; n < 4; ++n) {
    const int col = bn * 128 + wn * 64 + n * 16 + lr;
    const float bv = bias[col];
#pragma unroll
    for (int m = 0; m < 4; ++m) {
#pragma unroll
      for (int r = 0; r < 4; ++r) {
        const size_t row = a0 + wm * 64 + m * 16 + lk * 4 + r;
        float v = acc[m][n][r] + bv;
        if (gelu) v = geluf(v);
        C[row * (size_t)N + col] = f2bf(v);
      }
    }
  }
}

// ---------------- scatter qkv (L,3072) -> q/k (H,L,64), v -> VT (H,64,L) ----
__global__ __launch_bounds__(256) void qkv_scatter(
    const u16* __restrict__ t, u16* __restrict__ q, u16* __restrict__ k,
    u16* __restrict__ vt) {
  const int idx = blockIdx.x * 256 + threadIdx.x;  // 8-elem chunk
  const int l = idx / 384, r = idx % 384;
  const int col = r * 8;
  const int which = col >> 10, rem = col & 1023;
  const int h = rem >> 6, d = rem & 63;
  uint4 val = *(const uint4*)&t[(size_t)l * 3072 + col];
  if (which == 0) {
    *(uint4*)&q[((size_t)h * LTOT + l) * HD + d] = val;
  } else if (which == 1) {
    *(uint4*)&k[((size_t)h * LTOT + l) * HD + d] = val;
  } else {
    const u16* vp = (const u16*)&val;
#pragma unroll
    for (int j = 0; j < 8; ++j)
      vt[((size_t)h * HD + d + j) * LTOT + l] = vp[j];
  }
}

// ---------------- RMS norm + RoPE on q,k (bf16), one wave per (h,l) ---------
__global__ __launch_bounds__(256) void rmsrope(
    u16* __restrict__ q, u16* __restrict__ k, const float* __restrict__ pe,
    const float* __restrict__ iqs, const float* __restrict__ iks,
    const float* __restrict__ tqs, const float* __restrict__ tks) {
  const int gw = (blockIdx.x * 256 + threadIdx.x) >> 6;
  const int lane = threadIdx.x & 63;
  const int l = gw % LTOT, h = gw / LTOT;
  const float* qs = (l < LTXT) ? tqs : iqs;
  const float* ks = (l < LTXT) ? tks : iks;
  const size_t base = ((size_t)h * LTOT + l) * HD + lane;
  const float* peb = pe + (size_t)l * 128 + (lane >> 1) * 4 + (lane & 1) * 2;
  {
    float x = bf2f(q[base]);
    float ss = x * x;
#pragma unroll
    for (int o = 32; o; o >>= 1) ss += __shfl_xor(ss, o);
    float xn = x * rsqrtf(ss * (1.f / HD) + 1e-6f) * qs[lane];
    float part = __shfl_xor(xn, 1);
    float x0 = (lane & 1) ? part : xn;
    float x1 = (lane & 1) ? xn : part;
    q[base] = f2bf(peb[0] * x0 + peb[1] * x1);
  }
  {
    float x = bf2f(k[base]);
    float ss = x * x;
#pragma unroll
    for (int o = 32; o; o >>= 1) ss += __shfl_xor(ss, o);
    float xn = x * rsqrtf(ss * (1.f / HD) + 1e-6f) * ks[lane];
    float part = __shfl_xor(xn, 1);
    float x0 = (lane & 1) ? part : xn;
    float x1 = (lane & 1) ? xn : part;
    k[base] = f2bf(peb[0] * x0 + peb[1] * x1);
  }
}

// ---------------- MFMA flash attention: 4 waves, BQ=64, KV-tile 64 ----------
// Q,K: (H,L,64) bf16; VT: (H,64,L) bf16; out: (L,1024) bf16
__global__ __launch_bounds__(256) void attn_mfma(
    const u16* __restrict__ Q, const u16* __restrict__ Kg,
    const u16* __restrict__ VT, u16* __restrict__ out) {
  __shared__ __align__(16) u16 Ks[64 * 64];
  __shared__ __align__(16) u16 Vs[64 * 64];
  __shared__ __align__(16) u16 Pw[4][16 * 64];
  const int tid = threadIdx.x, lane = tid & 63, w = tid >> 6;
  const int lr = lane & 15, lk = lane >> 4;
  const int h = blockIdx.y, q0 = blockIdx.x * 64;
  const size_t hb = (size_t)h * LTOT;
  char* KsB = (char*)Ks;
  char* VsB = (char*)Vs;
  char* PwB = (char*)&Pw[w][0];
  const int swzr = (lr & 7) << 4;

  bf16x8 qa0 = *(const bf16x8*)&Q[(hb + q0 + w * 16 + lr) * HD + lk * 8];
  bf16x8 qa1 = *(const bf16x8*)&Q[(hb + q0 + w * 16 + lr) * HD + 32 + lk * 8];
  float m_run[4] = {-1e30f, -1e30f, -1e30f, -1e30f};
  float l_run[4] = {0.f, 0.f, 0.f, 0.f};
  f32x4 acc[4] = {};

  for (int k0 = 0; k0 < LTOT; k0 += 64) {
#pragma unroll
    for (int i = 0; i < 2; ++i) {
      const int c = tid + i * 256;
      const int row = c >> 3, off8 = c & 7;
      uint4 kv = *(const uint4*)&Kg[(hb + k0 + row) * HD + off8 * 8];
      *(uint4*)(KsB + ((row * 128 + off8 * 16) ^ ((row & 7) << 4))) = kv;
      uint4 vv = *(const uint4*)&VT[((size_t)h * HD + row) * LTOT + k0 + off8 * 8];
      *(uint4*)(VsB + ((row * 128 + off8 * 16) ^ ((row & 7) << 4))) = vv;
    }
    __syncthreads();
    // QK^T: S[q=(lk*4+r)][key=g*16+lr]
    f32x4 s[4];
#pragma unroll
    for (int g = 0; g < 4; ++g) {
      const int krow = g * 16 + lr;
      const int rb = krow * 128, sw = (krow & 7) << 4;
      bf16x8 kb0 = *(const bf16x8*)(KsB + ((rb + lk * 16) ^ sw));
      bf16x8 kb1 = *(const bf16x8*)(KsB + ((rb + 64 + lk * 16) ^ sw));
      f32x4 z = {0.f, 0.f, 0.f, 0.f};
      z = __builtin_amdgcn_mfma_f32_16x16x32_bf16(qa0, kb0, z, 0, 0, 0);
      z = __builtin_amdgcn_mfma_f32_16x16x32_bf16(qa1, kb1, z, 0, 0, 0);
      s[g] = z;
    }
    // online softmax (scale 1/8)
    float al[4];
#pragma unroll
    for (int r = 0; r < 4; ++r) {
      float mx = fmaxf(fmaxf(s[0][r], s[1][r]), fmaxf(s[2][r], s[3][r]));
      mx = fmaxf(mx, __shfl_xor(mx, 1));
      mx = fmaxf(mx, __shfl_xor(mx, 2));
      mx = fmaxf(mx, __shfl_xor(mx, 4));
      mx = fmaxf(mx, __shfl_xor(mx, 8));
      const float mnew = fmaxf(m_run[r], mx * 0.125f);
      al[r] = __expf(m_run[r] - mnew);
      m_run[r] = mnew;
      const int prow = lk * 4 + r;
      const int pb = prow * 128, psw = (prow & 7) << 4;
      float ps = 0.f;
#pragma unroll
      for (int g = 0; g < 4; ++g) {
        float p = __expf(s[g][r] * 0.125f - mnew);
        ps += p;
        *(u16*)(PwB + ((pb + (g * 16 + lr) * 2) ^ psw)) = f2bf(p);
      }
      ps += __shfl_xor(ps, 1);
      ps += __shfl_xor(ps, 2);
      ps += __shfl_xor(ps, 4);
      ps += __shfl_xor(ps, 8);
      l_run[r] = l_run[r] * al[r] + ps;
    }
#pragma unroll
    for (int dt = 0; dt < 4; ++dt) {
      f32x4 t = acc[dt];
      t[0] *= al[0]; t[1] *= al[1]; t[2] *= al[2]; t[3] *= al[3];
      acc[dt] = t;
    }
    // PV: A = P(16q x 32key), B = V(32key x 16d) from Vs rows=d
#pragma unroll
    for (int ks = 0; ks < 2; ++ks) {
      bf16x8 pa = *(const bf16x8*)(PwB + ((lr * 128 + ks * 64 + lk * 16) ^ swzr));
#pragma unroll
      for (int dt = 0; dt < 4; ++dt) {
        const int vrow = dt * 16 + lr;
        bf16x8 vb = *(const bf16x8*)(VsB + ((vrow * 128 + ks * 64 + lk * 16) ^
                                            ((vrow & 7) << 4)));
        acc[dt] = __builtin_amdgcn_mfma_f32_16x16x32_bf16(pa, vb, acc[dt], 0, 0, 0);
      }
    }
    __syncthreads();
  }
#pragma unroll
  for (int dt = 0; dt < 4; ++dt)
#pragma unroll
    for (int r = 0; r < 4; ++r)
      out[(size_t)(q0 + w * 16 + lk * 4 + r) * DD + h * HD + dt * 16 + lr] =
          f2bf(acc[dt][r] / l_run[r]);
}

// ---------------- gated residual: out = xin + g[col] * bf16(t) --------------
__global__ __launch_bounds__(256) void resid_gate(
    const float* __restrict__ xin, const u16* __restrict__ t,
    const float* __restrict__ g, float* __restrict__ out, int n4) {
  const int idx = blockIdx.x * 256 + threadIdx.x;
  if (idx >= n4) return;
  const int col = (idx * 4) & (DD - 1);
  const float4 a = ((const float4*)xin)[idx];
  const ushort4 tb = ((const ushort4*)t)[idx];
  const float4 gg = *(const float4*)&g[col];
  float4 r;
  r.x = a.x + gg.x * bf2f(tb.x);
  r.y = a.y + gg.y * bf2f(tb.y);
  r.z = a.z + gg.z * bf2f(tb.z);
  r.w = a.w + gg.w * bf2f(tb.w);
  ((float4*)out)[idx] = r;
}

extern "C" void kernel_launch(void* const* d_in, const int* in_sizes, int n_in,
                              void* d_out, int out_size, void* d_ws,
                              size_t ws_size, hipStream_t stream) {
  const float* img = (const float*)d_in[0];
  const float* txt = (const float*)d_in[1];
  const float* vec = (const float*)d_in[2];
  const float* pe = (const float*)d_in[3];
  const float* i_mod_w = (const float*)d_in[4];
  const float* i_mod_b = (const float*)d_in[5];
  const float* i_n1s = (const float*)d_in[6];
  const float* i_n1b = (const float*)d_in[7];
  const float* i_qkv_w = (const float*)d_in[8];
  const float* i_qkv_b = (const float*)d_in[9];
  const float* i_qs = (const float*)d_in[10];
  const float* i_ks = (const float*)d_in[11];
  const float* i_proj_w = (const float*)d_in[12];
  const float* i_proj_b = (const float*)d_in[13];
  const float* i_n2s = (const float*)d_in[14];
  const float* i_n2b = (const float*)d_in[15];
  const float* i_w1 = (const float*)d_in[16];
  const float* i_b1 = (const float*)d_in[17];
  const float* i_w2 = (const float*)d_in[18];
  const float* i_b2 = (const float*)d_in[19];
  const float* t_mod_w = (const float*)d_in[20];
  const float* t_mod_b = (const float*)d_in[21];
  const float* t_n1s = (const float*)d_in[22];
  const float* t_n1b = (const float*)d_in[23];
  const float* t_qkv_w = (const float*)d_in[24];
  const float* t_qkv_b = (const float*)d_in[25];
  const float* t_qs = (const float*)d_in[26];
  const float* t_ks = (const float*)d_in[27];
  const float* t_proj_w = (const float*)d_in[28];
  const float* t_proj_b = (const float*)d_in[29];
  const float* t_n2s = (const float*)d_in[30];
  const float* t_n2b = (const float*)d_in[31];
  const float* t_w1 = (const float*)d_in[32];
  const float* t_b1 = (const float*)d_in[33];
  const float* t_w2 = (const float*)d_in[34];
  const float* t_b2 = (const float*)d_in[35];

  const size_t LD = (size_t)LTOT * DD;
  uint8_t* p = (uint8_t*)d_ws;
  float* modb = (float*)p;           p += 64 * 1024;
  u16* tqkvT = (u16*)p;              p += (size_t)3072 * 1024 * 2;
  u16* iqkvT = (u16*)p;              p += (size_t)3072 * 1024 * 2;
  u16* tprojT = (u16*)p;             p += (size_t)1024 * 1024 * 2;
  u16* iprojT = (u16*)p;             p += (size_t)1024 * 1024 * 2;
  u16* tw1T = (u16*)p;               p += (size_t)4096 * 1024 * 2;
  u16* iw1T = (u16*)p;               p += (size_t)4096 * 1024 * 2;
  u16* tw2T = (u16*)p;               p += (size_t)1024 * 4096 * 2;
  u16* iw2T = (u16*)p;               p += (size_t)1024 * 4096 * 2;
  u16* actA = (u16*)p;               p += LD * 2;                  // xm / attnout
  u16* actB = (u16*)p;               p += (size_t)LTOT * DMLP * 2; // qkvtmp / mid
  u16* actC = (u16*)p;               p += LD * 2 * 3;              // q,k,vt / proj,h2,mlp2
  float* out_img = (float*)d_out;
  float* out_txt = out_img + (size_t)LIMG * DD;

  // 0. weight transpose+cast to bf16
  wcast_t<<<dim3(96, 32), 256, 0, stream>>>(t_qkv_w, tqkvT, 1024, 3072);
  wcast_t<<<dim3(96, 32), 256, 0, stream>>>(i_qkv_w, iqkvT, 1024, 3072);
  wcast_t<<<dim3(32, 32), 256, 0, stream>>>(t_proj_w, tprojT, 1024, 1024);
  wcast_t<<<dim3(32, 32), 256, 0, stream>>>(i_proj_w, iprojT, 1024, 1024);
  wcast_t<<<dim3(128, 32), 256, 0, stream>>>(t_w1, tw1T, 1024, 4096);
  wcast_t<<<dim3(128, 32), 256, 0, stream>>>(i_w1, iw1T, 1024, 4096);
  wcast_t<<<dim3(32, 128), 256, 0, stream>>>(t_w2, tw2T, 4096, 1024);
  wcast_t<<<dim3(32, 128), 256, 0, stream>>>(i_w2, iw2T, 4096, 1024);
  // 1. modulation
  mod_gemv<<<dim3(24, 2), 256, 0, stream>>>(vec, i_mod_w, i_mod_b, t_mod_w,
                                            t_mod_b, modb);
  // 2. LN1+mod -> actA (bf16; txt rows first)
  ln_mod_kernel<<<LTXT, 256, 0, stream>>>(txt, actA, t_n1s, t_n1b, modb + 6144,
                                          0, 1024);
  ln_mod_kernel<<<LIMG, 256, 0, stream>>>(img, actA + (size_t)LTXT * DD, i_n1s,
                                          i_n1b, modb, 0, 1024);
  // 3. QKV GEMM -> actB (L,3072)
  gemm_mfma<<<dim3(24, 20), 256, 0, stream>>>(actA, tqkvT, iqkvT, t_qkv_b,
                                              i_qkv_b, actB, 1024, 3072, 0);
  // 4. scatter (V transposed globally)
  qkv_scatter<<<3840, 256, 0, stream>>>(actB, actC, actC + LD, actC + 2 * LD);
  // 5. RMS + RoPE
  rmsrope<<<10240, 256, 0, stream>>>(actC, actC + LD, pe, i_qs, i_ks, t_qs,
                                     t_ks);
  // 6. attention -> actA (L,1024)
  attn_mfma<<<dim3(40, 16), 256, 0, stream>>>(actC, actC + LD, actC + 2 * LD,
                                              actA);
  // 7. proj GEMM -> actC
  gemm_mfma<<<dim3(8, 20), 256, 0, stream>>>(actA, tprojT, iprojT, t_proj_b,
                                             i_proj_b, actC, 1024, 1024, 0);
  // 8. residual 1 -> d_out
  resid_gate<<<2048, 256, 0, stream>>>(img, actC + (size_t)LTXT * DD,
                                       modb + 2048, out_img, LIMG * DD / 4);
  resid_gate<<<512, 256, 0, stream>>>(txt, actC, modb + 6144 + 2048, out_txt,
                                      LTXT * DD / 4);
  // 9. LN2+mod -> actC+LD (h2)
  ln_mod_kernel<<<LTXT, 256, 0, stream>>>(out_txt, actC + LD, t_n2s, t_n2b,
                                          modb + 6144, 3072, 4096);
  ln_mod_kernel<<<LIMG, 256, 0, stream>>>(out_img, actC + LD + (size_t)LTXT * DD,
                                          i_n2s, i_n2b, modb, 3072, 4096);
  // 10. MLP1+GELU -> actB (L,4096)
  gemm_mfma<<<dim3(32, 20), 256, 0, stream>>>(actC + LD, tw1T, iw1T, t_b1,
                                              i_b1, actB, 1024, 4096, 1);
  // 11. MLP2 -> actC+2LD
  gemm_mfma<<<dim3(8, 20), 256, 0, stream>>>(actB, tw2T, iw2T, t_b2, i_b2,
                                             actC + 2 * LD, 4096, 1024, 0);
  // 12. residual 2 (in place)
  resid_gate<<<2048, 256, 0, stream>>>(out_img,
                                       actC + 2 * LD + (size_t)LTXT * DD,
                                       modb + 5120, out_img, LIMG * DD / 4);
  resid_gate<<<512, 256, 0, stream>>>(out_txt, actC + 2 * LD,
                                      modb + 6144 + 5120, out_txt,
                                      LTXT * DD / 4);
}